// Round 2
// 365.825 us; speedup vs baseline: 1.1906x; 1.1906x over previous
//
#include <hip/hip_runtime.h>
#include <math.h>

#define L_SEQ 16384
#define BATCH 2
#define BL (BATCH * L_SEQ)      // 32768
#define DIN 256                 // D_INNER
#define DIMC 128                // DIM
#define NST 16                  // D_STATE
#define DTR 8                   // DT_RANK
#define CL 32                   // chunk length for scan
#define NC (L_SEQ / CL)         // 512 chunks per batch

// ---------------- K0: layernorm stats (mean, rstd) per position ----------------
__global__ __launch_bounds__(256) void k_ln_stats(const float* __restrict__ x,
                                                  float* __restrict__ mu,
                                                  float* __restrict__ rstd) {
    int p = blockIdx.x * 256 + threadIdx.x;   // 0..BL-1
    int b = p / L_SEQ, l = p % L_SEQ;
    const float* xb = x + (size_t)b * DIMC * L_SEQ + l;
    float s = 0.f, s2 = 0.f;
    for (int c = 0; c < DIMC; c++) {
        float v = xb[(size_t)c * L_SEQ];
        s += v; s2 += v * v;
    }
    float m = s * (1.f / DIMC);
    float var = s2 * (1.f / DIMC) - m * m;
    mu[p] = m;
    rstd[p] = rsqrtf(var + 1e-6f);
}

// ---------------- K1: fused LN + in_proj GEMM: xz(BL x 512) = xn(BL x 128) @ W1^T ----------------
// 128x128 block tile, 256 threads, 2x2x4x4 micro-tile (64 FMA / 64 B LDS = 2 flop/byte).
// Inner-loop LDS reads: a0/a1 broadcast within 16-lane groups, b0/b1 2-way (free on gfx950).
__global__ __launch_bounds__(256) void k_inproj(const float* __restrict__ x,
                                                const float* __restrict__ mu,
                                                const float* __restrict__ rstd,
                                                const float* __restrict__ nw,
                                                const float* __restrict__ nb,
                                                const float* __restrict__ w1,
                                                float* __restrict__ xz) {
    // grid: (BL/128, 512/128) = (256, 4)
    __shared__ float As[32][132];   // [c][pos]  (132*4 = 528 B, %16==0 -> aligned b128)
    __shared__ float Bs[32][132];   // [c][o]
    int bl0 = blockIdx.x * 128;
    int b = bl0 / L_SEQ;
    int l0 = bl0 % L_SEQ;
    int o0 = blockIdx.y * 128;
    int tid = threadIdx.x;
    int tx = tid & 15, ty = tid >> 4;

    // Each thread's staging quad along pos is invariant across chunks: hoist mu/rstd.
    int i4 = tid & 31;
    float4 m4 = *(const float4*)&mu[bl0 + i4 * 4];
    float4 r4 = *(const float4*)&rstd[bl0 + i4 * 4];

    float acc[2][2][4][4] = {};
    for (int c0 = 0; c0 < 128; c0 += 32) {
        __syncthreads();
        // As: 32 c x 128 pos; q = tid + k*256 -> c = (tid>>5)+8k, i4 = tid&31
        #pragma unroll
        for (int k = 0; k < 4; k++) {
            int c = (tid >> 5) + 8 * k;
            int cg = c0 + c;
            float4 v = *(const float4*)&x[((size_t)b * DIMC + cg) * L_SEQ + l0 + i4 * 4];
            float w = nw[cg], bb2 = nb[cg];
            float4 r;
            r.x = (v.x - m4.x) * r4.x * w + bb2;
            r.y = (v.y - m4.y) * r4.y * w + bb2;
            r.z = (v.z - m4.z) * r4.z * w + bb2;
            r.w = (v.w - m4.w) * r4.w * w + bb2;
            *(float4*)&As[c][i4 * 4] = r;   // consecutive lanes -> consecutive 16B: conflict-free
        }
        // Bs: transpose w1[o][c] -> Bs[c][o]; q: cq = q&7, o = q>>3 (128B-coalesced global reads)
        #pragma unroll
        for (int k = 0; k < 4; k++) {
            int q = tid + k * 256;
            int cq = q & 7, o = q >> 3;
            float4 v = *(const float4*)&w1[(size_t)(o0 + o) * 128 + c0 + cq * 4];
            Bs[cq * 4 + 0][o] = v.x;
            Bs[cq * 4 + 1][o] = v.y;
            Bs[cq * 4 + 2][o] = v.z;
            Bs[cq * 4 + 3][o] = v.w;
        }
        __syncthreads();
        #pragma unroll 4
        for (int c = 0; c < 32; c++) {
            float4 a0 = *(const float4*)&As[c][ty * 4];
            float4 a1 = *(const float4*)&As[c][ty * 4 + 64];
            float4 b0 = *(const float4*)&Bs[c][tx * 4];
            float4 b1 = *(const float4*)&Bs[c][tx * 4 + 64];
            float av[2][4] = {{a0.x, a0.y, a0.z, a0.w}, {a1.x, a1.y, a1.z, a1.w}};
            float bv[2][4] = {{b0.x, b0.y, b0.z, b0.w}, {b1.x, b1.y, b1.z, b1.w}};
            #pragma unroll
            for (int ih = 0; ih < 2; ih++)
                #pragma unroll
                for (int jh = 0; jh < 2; jh++)
                    #pragma unroll
                    for (int ii = 0; ii < 4; ii++)
                        #pragma unroll
                        for (int jj = 0; jj < 4; jj++)
                            acc[ih][jh][ii][jj] += av[ih][ii] * bv[jh][jj];
        }
    }
    #pragma unroll
    for (int ih = 0; ih < 2; ih++)
        #pragma unroll
        for (int ii = 0; ii < 4; ii++) {
            size_t p = (size_t)bl0 + ih * 64 + ty * 4 + ii;
            #pragma unroll
            for (int jh = 0; jh < 2; jh++) {
                float4 v = make_float4(acc[ih][jh][ii][0], acc[ih][jh][ii][1],
                                       acc[ih][jh][ii][2], acc[ih][jh][ii][3]);
                *(float4*)&xz[p * 512 + o0 + jh * 64 + tx * 4] = v;
            }
        }
}

// ---------------- K2: causal depthwise conv (k=4) + silu -> x_in ----------------
// 16 positions per block, rolling register window: each xz row read exactly once.
__global__ __launch_bounds__(256) void k_conv(const float* __restrict__ xz,
                                              const float* __restrict__ cw,
                                              const float* __restrict__ cb,
                                              float* __restrict__ xin) {
    int blk = blockIdx.x;            // BL/16 blocks
    int d = threadIdx.x;             // 0..255
    int p0 = blk * 16;
    int b = p0 / L_SEQ, t0 = p0 % L_SEQ;
    float w0 = cw[d * 4 + 0], w1v = cw[d * 4 + 1], w2 = cw[d * 4 + 2], w3 = cw[d * 4 + 3];
    float bias = cb[d];
    const float* base = xz + (size_t)b * L_SEQ * 512 + d;
    float vm3 = (t0 >= 3) ? base[(size_t)(t0 - 3) * 512] : 0.f;
    float vm2 = (t0 >= 2) ? base[(size_t)(t0 - 2) * 512] : 0.f;
    float vm1 = (t0 >= 1) ? base[(size_t)(t0 - 1) * 512] : 0.f;
    #pragma unroll
    for (int i = 0; i < 16; i++) {
        float v = base[(size_t)(t0 + i) * 512];
        float a = bias + w0 * vm3 + w1v * vm2 + w2 * vm1 + w3 * v;
        float sig = 1.f / (1.f + __expf(-a));
        xin[(size_t)(p0 + i) * 256 + d] = a * sig;
        vm3 = vm2; vm2 = vm1; vm1 = v;
    }
}

// ---------------- K3: x_proj GEMM (256->40, padded to 64) + fused dt_proj (8->256) + softplus ----
__global__ __launch_bounds__(256) void k_xproj(const float* __restrict__ xin,
                                               const float* __restrict__ wx,
                                               const float* __restrict__ wdt,
                                               const float* __restrict__ bdt,
                                               float* __restrict__ dtb,
                                               float* __restrict__ Bmb,
                                               float* __restrict__ Cmb) {
    __shared__ float Xs[128 * 68];  // [c][pos_local]
    __shared__ float Ws[128 * 68];  // [c][o_local] (o >= 40 zero-padded)
    __shared__ float Dt8[64 * 8];   // x_dbl[:, :8] staging for dt_proj
    int bl0 = blockIdx.x * 64;
    int tid = threadIdx.x;
    int tx = tid & 15, ty = tid >> 4;  // tx -> output quad, ty -> position quad

    float acc[4][4] = {};              // [pos_off][o_off]
    for (int c0 = 0; c0 < 256; c0 += 128) {
        __syncthreads();
        for (int idx = tid; idx < 128 * 64; idx += 256) {
            int c = idx & 127, i = idx >> 7;   // lane -> c : coalesced global read
            Xs[c * 68 + i] = xin[(size_t)(bl0 + i) * 256 + c0 + c];
        }
        for (int idx = tid; idx < 128 * 64; idx += 256) {
            int c = idx & 127, o = idx >> 7;
            Ws[c * 68 + o] = (o < 40) ? wx[o * 256 + c0 + c] : 0.f;
        }
        __syncthreads();
        for (int c = 0; c < 128; c++) {
            float4 av = *(const float4*)&Xs[c * 68 + ty * 4];
            float4 bv = *(const float4*)&Ws[c * 68 + tx * 4];
            float a[4] = {av.x, av.y, av.z, av.w};
            float bb[4] = {bv.x, bv.y, bv.z, bv.w};
            #pragma unroll
            for (int ii = 0; ii < 4; ii++)
                #pragma unroll
                for (int jj = 0; jj < 4; jj++) acc[ii][jj] += a[ii] * bb[jj];
        }
    }

    // Scatter outputs: o in [0,8) -> Dt8 (LDS), [8,24) -> Bm, [24,40) -> Cm
    __syncthreads();
    if (tx < 2) {
        #pragma unroll
        for (int ii = 0; ii < 4; ii++)
            #pragma unroll
            for (int jj = 0; jj < 4; jj++)
                Dt8[(ty * 4 + ii) * 8 + tx * 4 + jj] = acc[ii][jj];
    } else if (tx < 6) {
        #pragma unroll
        for (int ii = 0; ii < 4; ii++) {
            size_t p = (size_t)(bl0 + ty * 4 + ii);
            float4 v = make_float4(acc[ii][0], acc[ii][1], acc[ii][2], acc[ii][3]);
            *(float4*)&Bmb[p * 16 + (tx - 2) * 4] = v;
        }
    } else if (tx < 10) {
        #pragma unroll
        for (int ii = 0; ii < 4; ii++) {
            size_t p = (size_t)(bl0 + ty * 4 + ii);
            float4 v = make_float4(acc[ii][0], acc[ii][1], acc[ii][2], acc[ii][3]);
            *(float4*)&Cmb[p * 16 + (tx - 6) * 4] = v;
        }
    }
    __syncthreads();

    // dt_proj: each thread owns channel d = tid, loops the 64 positions
    int d = tid;
    float bias = bdt[d];
    float w8[8];
    #pragma unroll
    for (int r = 0; r < 8; r++) w8[r] = wdt[d * 8 + r];
    for (int p = 0; p < 64; p++) {
        float4 xa = *(float4*)&Dt8[p * 8];
        float4 xb = *(float4*)&Dt8[p * 8 + 4];
        float a = bias;
        a += xa.x * w8[0] + xa.y * w8[1] + xa.z * w8[2] + xa.w * w8[3];
        a += xb.x * w8[4] + xb.y * w8[5] + xb.z * w8[6] + xb.w * w8[7];
        float sp = (a > 20.f) ? a : log1pf(__expf(a));
        dtb[(size_t)(bl0 + p) * 256 + d] = sp;
    }
}

// ---------------- K4a: scan phase 1 — per-chunk products & local states ----------------
__global__ __launch_bounds__(256) void k_scan1(const float* __restrict__ dtb,
                                               const float* __restrict__ xin,
                                               const float* __restrict__ Bmb,
                                               const float* __restrict__ Alog,
                                               float* __restrict__ Pb,
                                               float* __restrict__ Sb) {
    int blk = blockIdx.x;            // BATCH*NC blocks
    int b = blk / NC, ch = blk % NC;
    int d = threadIdx.x;
    int t0 = ch * CL;
    __shared__ float Bs[CL * 16];
    for (int idx = threadIdx.x; idx < CL * 16; idx += 256)
        Bs[idx] = Bmb[((size_t)(b * L_SEQ + t0)) * 16 + idx];
    float Ar[16];
    #pragma unroll
    for (int n = 0; n < 16; n++) Ar[n] = -__expf(Alog[d * 16 + n]);
    float P[16], S[16];
    #pragma unroll
    for (int n = 0; n < 16; n++) { P[n] = 1.f; S[n] = 0.f; }
    __syncthreads();
    for (int i = 0; i < CL; i++) {
        size_t p = (size_t)(b * L_SEQ + t0 + i);
        float dtv = dtb[p * 256 + d];
        float xv  = xin[p * 256 + d];
        float du = dtv * xv;
        #pragma unroll
        for (int n = 0; n < 16; n++) {
            float a = __expf(dtv * Ar[n]);
            P[n] *= a;
            S[n] = a * S[n] + du * Bs[i * 16 + n];
        }
    }
    size_t base = ((size_t)(b * NC + ch) * 16) * 256 + d;
    #pragma unroll
    for (int n = 0; n < 16; n++) {
        Pb[base + (size_t)n * 256] = P[n];
        Sb[base + (size_t)n * 256] = S[n];
    }
}

// ---------------- K4b: scan phase 2 — sequential over chunks, Sb becomes h_start ----------------
__global__ __launch_bounds__(256) void k_scan2(const float* __restrict__ Pb,
                                               float* __restrict__ Sb) {
    int id = blockIdx.x * 256 + threadIdx.x;  // 0..8191: (b,n,d)
    int d = id & 255;
    int n = (id >> 8) & 15;
    int b = id >> 12;
    float h = 0.f;
    for (int c = 0; c < NC; c++) {
        size_t ix = (((size_t)(b * NC + c) * 16) + n) * 256 + d;
        float Pv = Pb[ix];
        float Sv = Sb[ix];
        Sb[ix] = h;          // h_start for chunk c
        h = Pv * h + Sv;
    }
}

// ---------------- K4c: scan phase 3 — replay chunk from h_start, fuse D-skip + silu(z) gate ----------------
__global__ __launch_bounds__(256) void k_scan3(const float* __restrict__ dtb,
                                               const float* __restrict__ xin,
                                               const float* __restrict__ Bmb,
                                               const float* __restrict__ Cmb,
                                               const float* __restrict__ Alog,
                                               const float* __restrict__ Sb,
                                               const float* __restrict__ Dp,
                                               const float* __restrict__ xz,
                                               float* __restrict__ yg) {
    int blk = blockIdx.x;
    int b = blk / NC, ch = blk % NC;
    int d = threadIdx.x;
    int t0 = ch * CL;
    __shared__ float Bs[CL * 16], Cs[CL * 16];
    for (int idx = threadIdx.x; idx < CL * 16; idx += 256) {
        Bs[idx] = Bmb[((size_t)(b * L_SEQ + t0)) * 16 + idx];
        Cs[idx] = Cmb[((size_t)(b * L_SEQ + t0)) * 16 + idx];
    }
    float Ar[16], h[16];
    #pragma unroll
    for (int n = 0; n < 16; n++) Ar[n] = -__expf(Alog[d * 16 + n]);
    size_t base = ((size_t)(b * NC + ch) * 16) * 256 + d;
    #pragma unroll
    for (int n = 0; n < 16; n++) h[n] = Sb[base + (size_t)n * 256];
    float Dv = Dp[d];
    __syncthreads();
    for (int i = 0; i < CL; i++) {
        size_t p = (size_t)(b * L_SEQ + t0 + i);
        float dtv = dtb[p * 256 + d];
        float xv  = xin[p * 256 + d];
        float du = dtv * xv;
        float y = 0.f;
        #pragma unroll
        for (int n = 0; n < 16; n++) {
            float a = __expf(dtv * Ar[n]);
            h[n] = a * h[n] + du * Bs[i * 16 + n];
            y += h[n] * Cs[i * 16 + n];
        }
        float zv = xz[p * 512 + 256 + d];
        float sig = 1.f / (1.f + __expf(-zv));
        yg[p * 256 + d] = (y + xv * Dv) * (zv * sig);
    }
}

// ---------------- K5: out_proj GEMM, transposed output: out[b][c][t] = yg[b][t][:] . Wo[c][:] ----
// 128pos x 64c tile, 256 threads, 2x4x4 micro-tile (32 FMA / 48 B LDS).
__global__ __launch_bounds__(256) void k_outproj(const float* __restrict__ yg,
                                                 const float* __restrict__ wo,
                                                 float* __restrict__ out) {
    // grid: (BL/128, 128/64) = (256, 2); K=256 in 8 chunks of 32
    __shared__ float As[32][132];  // [k][t]
    __shared__ float Bs[32][68];   // [k][c]
    int bl0 = blockIdx.x * 128;
    int b = bl0 / L_SEQ;
    int t0 = bl0 % L_SEQ;
    int c0 = blockIdx.y * 64;
    int tid = threadIdx.x;
    int tx = tid & 15, ty = tid >> 4;   // tx -> pos quad (coalesced out writes), ty -> c quad

    float acc[2][4][4] = {};            // [pos_half][c_off][pos_off]
    for (int k0 = 0; k0 < 256; k0 += 32) {
        __syncthreads();
        // As: yg[(bl0+t)*256 + k0 + kq*4] -> As[kk][t]; 1024 quads, 4/thread
        #pragma unroll
        for (int k = 0; k < 4; k++) {
            int q = tid + k * 256;
            int kq = q & 7, t = q >> 3;
            float4 v = *(const float4*)&yg[(size_t)(bl0 + t) * 256 + k0 + kq * 4];
            As[kq * 4 + 0][t] = v.x;
            As[kq * 4 + 1][t] = v.y;
            As[kq * 4 + 2][t] = v.z;
            As[kq * 4 + 3][t] = v.w;
        }
        // Bs: wo[(c0+c)*256 + k0 + kq*4] -> Bs[kk][c]; 512 quads, 2/thread
        #pragma unroll
        for (int k = 0; k < 2; k++) {
            int q = tid + k * 256;
            int kq = q & 7, c = q >> 3;
            float4 v = *(const float4*)&wo[(size_t)(c0 + c) * 256 + k0 + kq * 4];
            Bs[kq * 4 + 0][c] = v.x;
            Bs[kq * 4 + 1][c] = v.y;
            Bs[kq * 4 + 2][c] = v.z;
            Bs[kq * 4 + 3][c] = v.w;
        }
        __syncthreads();
        #pragma unroll 4
        for (int k = 0; k < 32; k++) {
            float4 a0 = *(const float4*)&As[k][tx * 4];
            float4 a1 = *(const float4*)&As[k][tx * 4 + 64];
            float4 b0 = *(const float4*)&Bs[k][ty * 4];
            float av[2][4] = {{a0.x, a0.y, a0.z, a0.w}, {a1.x, a1.y, a1.z, a1.w}};
            float bv[4] = {b0.x, b0.y, b0.z, b0.w};
            #pragma unroll
            for (int ih = 0; ih < 2; ih++)
                #pragma unroll
                for (int j = 0; j < 4; j++)
                    #pragma unroll
                    for (int i = 0; i < 4; i++)
                        acc[ih][j][i] += av[ih][i] * bv[j];
        }
    }
    #pragma unroll
    for (int j = 0; j < 4; j++) {
        int c = c0 + ty * 4 + j;
        #pragma unroll
        for (int ih = 0; ih < 2; ih++) {
            float4 v = make_float4(acc[ih][j][0], acc[ih][j][1], acc[ih][j][2], acc[ih][j][3]);
            *(float4*)&out[((size_t)(b * 128 + c)) * L_SEQ + t0 + ih * 64 + tx * 4] = v;
        }
    }
}

extern "C" void kernel_launch(void* const* d_in, const int* in_sizes, int n_in,
                              void* d_out, int out_size, void* d_ws, size_t ws_size,
                              hipStream_t stream) {
    const float* x    = (const float*)d_in[0];
    const float* nw   = (const float*)d_in[1];
    const float* nb   = (const float*)d_in[2];
    const float* w1   = (const float*)d_in[3];
    const float* cw   = (const float*)d_in[4];
    const float* cb   = (const float*)d_in[5];
    const float* wx   = (const float*)d_in[6];
    const float* wdt  = (const float*)d_in[7];
    const float* bdt  = (const float*)d_in[8];
    const float* Alog = (const float*)d_in[9];
    const float* Dp   = (const float*)d_in[10];
    const float* wo   = (const float*)d_in[11];
    float* out = (float*)d_out;

    float* ws   = (float*)d_ws;
    float* xz   = ws;                       // BL*512 = 16,777,216
    float* mu   = xz + (size_t)BL * 512;    // 32768
    float* rstd = mu + BL;                  // 32768
    float* xin  = rstd + BL;                // BL*256 = 8,388,608
    float* dtb  = xin + (size_t)BL * 256;   // 8,388,608
    float* Bmb  = dtb + (size_t)BL * 256;   // 524,288
    float* Cmb  = Bmb + (size_t)BL * 16;    // 524,288
    float* Pb   = Cmb + (size_t)BL * 16;    // 2*NC*16*256 = 4,194,304
    float* Sb   = Pb + (size_t)BATCH * NC * 16 * 256;  // 4,194,304
    float* yg   = Sb + (size_t)BATCH * NC * 16 * 256;  // 8,388,608

    k_ln_stats<<<BL / 256, 256, 0, stream>>>(x, mu, rstd);
    k_inproj<<<dim3(BL / 128, 512 / 128), 256, 0, stream>>>(x, mu, rstd, nw, nb, w1, xz);
    k_conv<<<BL / 16, 256, 0, stream>>>(xz, cw, cb, xin);
    k_xproj<<<BL / 64, 256, 0, stream>>>(xin, wx, wdt, bdt, dtb, Bmb, Cmb);
    k_scan1<<<BATCH * NC, 256, 0, stream>>>(dtb, xin, Bmb, Alog, Pb, Sb);
    k_scan2<<<8192 / 256, 256, 0, stream>>>(Pb, Sb);
    k_scan3<<<BATCH * NC, 256, 0, stream>>>(dtb, xin, Bmb, Cmb, Alog, Sb, Dp, xz, yg);
    k_outproj<<<dim3(BL / 128, 128 / 64), 256, 0, stream>>>(yg, wo, out);
}